// Round 2
// baseline (734.142 us; speedup 1.0000x reference)
//
#include <hip/hip_runtime.h>

#define N_NODES 100000
#define DIM     128
#define RR      100
#define NB      4
#define NE      400000

typedef float  floatx4 __attribute__((ext_vector_type(4)));
typedef __bf16 bf16x8  __attribute__((ext_vector_type(8)));

static __device__ __forceinline__ unsigned short f2b(float f) {
    union { float f; unsigned int i; } v; v.f = f;
    unsigned int u = v.i;
    unsigned int r = (u + 0x7fffu + ((u >> 16) & 1u)) >> 16;   // round-nearest-even
    return (unsigned short)r;
}
static __device__ __forceinline__ float b2f(unsigned short u) {
    union { unsigned int i; float f; } v; v.i = ((unsigned int)u) << 16; return v.f;
}

// ---- schlichtkrull norm --------------------------------------------------
__global__ void k_count(const int* __restrict__ dst, const int* __restrict__ et,
                        int* __restrict__ counts, int E) {
    int e = blockIdx.x * 256 + threadIdx.x;
    if (e < E) atomicAdd(&counts[dst[e] * RR + et[e]], 1);
}

__global__ void k_norm(const int* __restrict__ dst, const int* __restrict__ et,
                       const int* __restrict__ counts, float* __restrict__ norm, int E) {
    int e = blockIdx.x * 256 + threadIdx.x;
    if (e < E) {
        int c = counts[dst[e] * RR + et[e]];
        norm[e] = 1.0f / (float)(c > 1 ? c : 1);
    }
}

// ---- x0 = relu(ent + ent_bias) fp32 -> bf16 ------------------------------
__global__ void k_x0(const float* __restrict__ ent, const float* __restrict__ entb,
                     unsigned short* __restrict__ x, int total) {
    int i = blockIdx.x * 256 + threadIdx.x;
    if (i < total) {
        float v = ent[i] + entb[i & (DIM - 1)];
        x[i] = f2b(v > 0.0f ? v : 0.0f);
    }
}

// ---- build bf16 WT[m][k]: m<512 -> bases[b=m>>7][k][h=m&127]; m>=512 -> root[k][m-512]
__global__ void k_prep(const float* __restrict__ bases1, const float* __restrict__ root1,
                       const float* __restrict__ bases2, const float* __restrict__ root2,
                       unsigned short* __restrict__ wt1, unsigned short* __restrict__ wt2) {
    int i = blockIdx.x * 256 + threadIdx.x;
    if (i >= 640 * 128) return;
    int m = i >> 7, k = i & 127;
    float v1, v2;
    if (m < 512) {
        int b = m >> 7, h = m & 127;
        v1 = bases1[(b * 128 + k) * 128 + h];
        v2 = bases2[(b * 128 + k) * 128 + h];
    } else {
        int h = m - 512;
        v1 = root1[k * 128 + h];
        v2 = root2[k * 128 + h];
    }
    wt1[m * 128 + k] = f2b(v1);
    wt2[m * 128 + k] = f2b(v2);
}

// ---- fused GEMM: [N,128](bf16) x [128,640](bf16) -> xb (cols 0..511, bf16)
// ----              and agg = x@root + bias (cols 512..639, fp32)
__global__ __launch_bounds__(256) void k_gemm(const unsigned short* __restrict__ X,
                                              const unsigned short* __restrict__ WT,
                                              const float* __restrict__ bias,
                                              unsigned short* __restrict__ xb,
                                              float* __restrict__ agg) {
    __shared__ __align__(16) unsigned short As[128 * 128];   // 32 KB, xor-swizzled 16B chunks
    __shared__ __align__(16) unsigned short Bs[128 * 128];   // 32 KB

    const int t = threadIdx.x;
    const int rbase = blockIdx.x * 128;
    const int cb = blockIdx.y;                               // 0..4 (col block of 128)

#pragma unroll
    for (int i = 0; i < 8; ++i) {
        int idx = i * 256 + t;
        int row = idx >> 4, ch = idx & 15;                   // 16 chunks of 16B per row
        int sch = (ch ^ (row & 15)) << 3;                    // xor swizzle, elem offset
        uint4 v = make_uint4(0u, 0u, 0u, 0u);
        int grow = rbase + row;
        if (grow < N_NODES) v = *(const uint4*)(X + (size_t)grow * 128 + ch * 8);
        *(uint4*)(As + row * 128 + sch) = v;
        uint4 w = *(const uint4*)(WT + (size_t)(cb * 128 + row) * 128 + ch * 8);
        *(uint4*)(Bs + row * 128 + sch) = w;
    }
    __syncthreads();

    const int wid = t >> 6, lane = t & 63;
    const int quad = lane >> 4, lr = lane & 15;
    const int wr = wid >> 1, wc = wid & 1;                   // wave quadrant in 128x128

    floatx4 acc[4][4];
#pragma unroll
    for (int i = 0; i < 4; ++i)
#pragma unroll
        for (int j = 0; j < 4; ++j) acc[i][j] = (floatx4)0.0f;

#pragma unroll
    for (int ks = 0; ks < 4; ++ks) {                         // K = 4 * 32
        bf16x8 a[4], b[4];
#pragma unroll
        for (int i = 0; i < 4; ++i) {
            int ar = wr * 64 + i * 16 + lr;                  // A row (m), low4 = lr
            int br = wc * 64 + i * 16 + lr;                  // B row (n)
            int sch = ((ks * 4 + quad) ^ lr) << 3;
            a[i] = *(const bf16x8*)(As + ar * 128 + sch);
            b[i] = *(const bf16x8*)(Bs + br * 128 + sch);
        }
#pragma unroll
        for (int i = 0; i < 4; ++i)
#pragma unroll
            for (int j = 0; j < 4; ++j)
                acc[i][j] = __builtin_amdgcn_mfma_f32_16x16x32_bf16(a[i], b[j], acc[i][j], 0, 0, 0);
    }

    // epilogue: C/D layout col=lane&15, row=quad*4+reg  [m89/m91-verified]
    if (cb < 4) {
#pragma unroll
        for (int i = 0; i < 4; ++i) {
            int r0 = rbase + wr * 64 + i * 16 + quad * 4;
#pragma unroll
            for (int reg = 0; reg < 4; ++reg) {
                int grow = r0 + reg;
                if (grow >= N_NODES) continue;
#pragma unroll
                for (int j = 0; j < 4; ++j) {
                    int col = cb * 128 + wc * 64 + j * 16 + lr;
                    xb[(size_t)grow * 512 + col] = f2b(acc[i][j][reg]);
                }
            }
        }
    } else {
#pragma unroll
        for (int i = 0; i < 4; ++i) {
            int r0 = rbase + wr * 64 + i * 16 + quad * 4;
#pragma unroll
            for (int reg = 0; reg < 4; ++reg) {
                int grow = r0 + reg;
                if (grow >= N_NODES) continue;
#pragma unroll
                for (int j = 0; j < 4; ++j) {
                    int col = wc * 64 + j * 16 + lr;
                    agg[(size_t)grow * 128 + col] = acc[i][j][reg] + bias[col];
                }
            }
        }
    }
}

// ---- per-edge basis mix + scatter-add ------------------------------------
__global__ __launch_bounds__(256) void k_edge(const unsigned short* __restrict__ xb,
                                              const int* __restrict__ src, const int* __restrict__ dst,
                                              const int* __restrict__ et, const float* __restrict__ norm,
                                              const float* __restrict__ comp,
                                              float* __restrict__ agg, int E) {
    int e = blockIdx.x * 2 + (threadIdx.x >> 7);
    if (e >= E) return;
    int h = threadIdx.x & 127;
    int s = src[e], d = dst[e], tt = et[e];
    float w = norm[e];
    float c0 = comp[tt * 4 + 0], c1 = comp[tt * 4 + 1];
    float c2 = comp[tt * 4 + 2], c3 = comp[tt * 4 + 3];
    const unsigned short* xr = xb + (size_t)s * 512;
    float m = c0 * b2f(xr[h]) + c1 * b2f(xr[128 + h]) + c2 * b2f(xr[256 + h]) + c3 * b2f(xr[384 + h]);
    atomicAdd(&agg[(size_t)d * 128 + h], w * m);
}

// ---- x = relu(agg) fp32 -> bf16 -----------------------------------------
__global__ void k_relu_cast(const float* __restrict__ agg, unsigned short* __restrict__ x, int total) {
    int i = blockIdx.x * 256 + threadIdx.x;
    if (i < total) {
        float v = agg[i];
        x[i] = f2b(v > 0.0f ? v : 0.0f);
    }
}

// ---- DistMult score: one wave per edge, all fp32 -------------------------
__global__ __launch_bounds__(256) void k_score(const float* __restrict__ xf,
                                               const int* __restrict__ src, const int* __restrict__ dst,
                                               const int* __restrict__ et, const float* __restrict__ rel,
                                               float* __restrict__ out, int E) {
    int wid = threadIdx.x >> 6, lane = threadIdx.x & 63;
    int e = blockIdx.x * 4 + wid;
    if (e >= E) return;
    int s = src[e], d = dst[e], tt = et[e];
    const float2 a = *(const float2*)(xf + (size_t)s * 128 + lane * 2);
    const float2 b = *(const float2*)(xf + (size_t)d * 128 + lane * 2);
    const float2 r = *(const float2*)(rel + (size_t)tt * 128 + lane * 2);
    float v = a.x * r.x * b.x + a.y * r.y * b.y;
#pragma unroll
    for (int o = 32; o > 0; o >>= 1) v += __shfl_down(v, o, 64);
    if (lane == 0) out[e] = v;
}

// ---- penalty = sum(rel^2), pure fp32 -------------------------------------
__global__ void k_penalty(const float* __restrict__ rel, float* __restrict__ out) {
    __shared__ float sm[256];
    float v = 0.0f;
    for (int i = threadIdx.x; i < RR * DIM; i += 256) { float x = rel[i]; v += x * x; }
    sm[threadIdx.x] = v;
    __syncthreads();
    for (int s = 128; s > 0; s >>= 1) {
        if (threadIdx.x < s) sm[threadIdx.x] += sm[threadIdx.x + s];
        __syncthreads();
    }
    if (threadIdx.x == 0) out[NE] = sm[0];
}

extern "C" void kernel_launch(void* const* d_in, const int* in_sizes, int n_in,
                              void* d_out, int out_size, void* d_ws, size_t ws_size,
                              hipStream_t stream) {
    (void)in_sizes; (void)n_in; (void)out_size; (void)ws_size;
    const int* edge_index = (const int*)d_in[0];            // [2,E]
    const int* edge_type  = (const int*)d_in[1];            // [E]
    const float* ent    = (const float*)d_in[2];
    const float* entb   = (const float*)d_in[3];
    const float* bases1 = (const float*)d_in[4];
    const float* comp1  = (const float*)d_in[5];
    const float* root1  = (const float*)d_in[6];
    const float* bias1  = (const float*)d_in[7];
    const float* bases2 = (const float*)d_in[8];
    const float* comp2  = (const float*)d_in[9];
    const float* root2  = (const float*)d_in[10];
    const float* bias2  = (const float*)d_in[11];
    const float* rel    = (const float*)d_in[12];
    const int* src = edge_index;
    const int* dst = edge_index + NE;

    char* ws = (char*)d_ws;
    size_t off = 0;
    float* norm = (float*)(ws + off);                  off += (size_t)NE * 4;            // 1.6 MB
    unsigned short* xbf = (unsigned short*)(ws + off); off += (size_t)N_NODES * 128 * 2; // 25.6 MB
    unsigned short* xb  = (unsigned short*)(ws + off); off += (size_t)N_NODES * 512 * 2; // 102.4 MB
    float* agg = (float*)(ws + off);                   off += (size_t)N_NODES * 128 * 4; // 51.2 MB
    unsigned short* wt1 = (unsigned short*)(ws + off); off += 640 * 128 * 2;
    unsigned short* wt2 = (unsigned short*)(ws + off); off += 640 * 128 * 2;
    int* counts = (int*)xb;                            // 40 MB alias; dead before xb is written

    float* out = (float*)d_out;

    hipMemsetAsync(counts, 0, (size_t)N_NODES * RR * 4, stream);
    k_count<<<(NE + 255) / 256, 256, 0, stream>>>(dst, edge_type, counts, NE);
    k_norm <<<(NE + 255) / 256, 256, 0, stream>>>(dst, edge_type, counts, norm, NE);
    k_x0   <<<(N_NODES * 128 + 255) / 256, 256, 0, stream>>>(ent, entb, xbf, N_NODES * 128);
    k_prep <<<(640 * 128 + 255) / 256, 256, 0, stream>>>(bases1, root1, bases2, root2, wt1, wt2);

    dim3 ggrid((N_NODES + 127) / 128, 5);
    // layer 1
    k_gemm<<<ggrid, 256, 0, stream>>>(xbf, wt1, bias1, xb, agg);
    k_edge<<<(NE + 1) / 2, 256, 0, stream>>>(xb, src, dst, edge_type, norm, comp1, agg, NE);
    k_relu_cast<<<(N_NODES * 128 + 255) / 256, 256, 0, stream>>>(agg, xbf, N_NODES * 128);
    // layer 2 (no relu after; agg holds final x)
    k_gemm<<<ggrid, 256, 0, stream>>>(xbf, wt2, bias2, xb, agg);
    k_edge<<<(NE + 1) / 2, 256, 0, stream>>>(xb, src, dst, edge_type, norm, comp2, agg, NE);
    // decode
    k_score<<<(NE + 3) / 4, 256, 0, stream>>>(agg, src, dst, edge_type, rel, out, NE);
    k_penalty<<<1, 256, 0, stream>>>(rel, out);
}

// Round 3
// 516.318 us; speedup vs baseline: 1.4219x; 1.4219x over previous
//
#include <hip/hip_runtime.h>

#define N_NODES 100000
#define DIM     128
#define RR      100
#define NE      400000
#define NBLK    196   // ceil(N_NODES / 512)

typedef float  floatx4 __attribute__((ext_vector_type(4)));
typedef __bf16 bf16x8  __attribute__((ext_vector_type(8)));

static __device__ __forceinline__ unsigned short f2b(float f) {
    union { float f; unsigned int i; } v; v.f = f;
    unsigned int u = v.i;
    unsigned int r = (u + 0x7fffu + ((u >> 16) & 1u)) >> 16;   // RNE
    return (unsigned short)r;
}
static __device__ __forceinline__ float b2f(unsigned int u16) {
    union { unsigned int i; float f; } v; v.i = u16 << 16; return v.f;
}

// ---- histogram: per-(dst,rel) counts + per-dst degree --------------------
__global__ void k_count(const int* __restrict__ dst, const int* __restrict__ et,
                        int* __restrict__ counts, int* __restrict__ deg, int E) {
    int e = blockIdx.x * 256 + threadIdx.x;
    if (e < E) {
        int d = dst[e];
        atomicAdd(&counts[d * RR + et[e]], 1);
        atomicAdd(&deg[d], 1);
    }
}

// ---- 2-level exclusive scan over deg[N] ----------------------------------
__global__ void k_scan_block(const int* __restrict__ deg, int* __restrict__ bsum) {
    __shared__ int sm[256];
    int b = blockIdx.x, t = threadIdx.x;
    int i0 = b * 512 + 2 * t;
    int a = (i0     < N_NODES) ? deg[i0]     : 0;
    int c = (i0 + 1 < N_NODES) ? deg[i0 + 1] : 0;
    sm[t] = a + c;
    __syncthreads();
    for (int s = 128; s > 0; s >>= 1) { if (t < s) sm[t] += sm[t + s]; __syncthreads(); }
    if (t == 0) bsum[b] = sm[0];
}

__global__ void k_scan_top(const int* __restrict__ bsum, int* __restrict__ boff) {
    __shared__ int sm[256];
    int t = threadIdx.x;
    int v = (t < NBLK) ? bsum[t] : 0;
    sm[t] = v;
    __syncthreads();
    for (int s = 1; s < 256; s <<= 1) {
        int u = (t >= s) ? sm[t - s] : 0;
        __syncthreads();
        sm[t] += u;
        __syncthreads();
    }
    if (t < NBLK) boff[t] = sm[t] - v;   // exclusive
}

__global__ void k_scan_down(const int* __restrict__ deg, const int* __restrict__ boff,
                            int* __restrict__ off) {
    __shared__ int sm[256];
    int b = blockIdx.x, t = threadIdx.x;
    int i0 = b * 512 + 2 * t;
    int a = (i0     < N_NODES) ? deg[i0]     : 0;
    int c = (i0 + 1 < N_NODES) ? deg[i0 + 1] : 0;
    int ts = a + c;
    sm[t] = ts;
    __syncthreads();
    for (int s = 1; s < 256; s <<= 1) {
        int u = (t >= s) ? sm[t - s] : 0;
        __syncthreads();
        sm[t] += u;
        __syncthreads();
    }
    int base = boff[b] + (sm[t] - ts);
    if (i0     < N_NODES) off[i0]     = base;
    if (i0 + 1 < N_NODES) off[i0 + 1] = base + a;
    if (b == 0 && t == 0) off[N_NODES] = NE;
}

// ---- scatter edges into dst-sorted CSR; fold in schlichtkrull norm -------
__global__ void k_scatter(const int* __restrict__ src, const int* __restrict__ dst,
                          const int* __restrict__ et, const int* __restrict__ counts,
                          const int* __restrict__ off, int* __restrict__ cursor,
                          int* __restrict__ ssrc, int* __restrict__ set_,
                          float* __restrict__ snorm, int E) {
    int e = blockIdx.x * 256 + threadIdx.x;
    if (e >= E) return;
    int d = dst[e], t = et[e];
    int c = counts[d * RR + t];                 // >=1 always
    int pos = off[d] + atomicAdd(&cursor[d], 1);
    ssrc[pos] = src[e];
    set_[pos] = t;
    snorm[pos] = 1.0f / (float)c;
}

// ---- x0 = relu(ent + ent_bias) fp32 -> bf16 ------------------------------
__global__ void k_x0(const float* __restrict__ ent, const float* __restrict__ entb,
                     unsigned short* __restrict__ x, int total) {
    int i = blockIdx.x * 256 + threadIdx.x;
    if (i < total) {
        float v = ent[i] + entb[i & (DIM - 1)];
        x[i] = f2b(v > 0.0f ? v : 0.0f);
    }
}

// ---- weight prep: wt[m=outcol][k 0..639] = (bases stacked ; root), bf16 --
__global__ void k_prep(const float* __restrict__ bases1, const float* __restrict__ root1,
                       const float* __restrict__ bases2, const float* __restrict__ root2,
                       const float* __restrict__ rel,
                       unsigned short* __restrict__ wt1, unsigned short* __restrict__ wt2,
                       unsigned short* __restrict__ relb) {
    int i = blockIdx.x * 256 + threadIdx.x;
    if (i < 128 * 640) {
        int m = i / 640, k = i % 640;
        float v1, v2;
        if (k < 512) {
            int b = k >> 7, kin = k & 127;
            v1 = bases1[(b * 128 + kin) * 128 + m];
            v2 = bases2[(b * 128 + kin) * 128 + m];
        } else {
            int kin = k - 512;
            v1 = root1[kin * 128 + m];
            v2 = root2[kin * 128 + m];
        }
        wt1[i] = f2b(v1);
        wt2[i] = f2b(v2);
    }
    if (i < RR * DIM) relb[i] = f2b(rel[i]);
}

// ---- pre-projection aggregation: one wave per dst node -------------------
// s[d, b*128 + c] = sum_e norm_e * comp[et_e, b] * x[src_e, c]
__global__ __launch_bounds__(256) void k_agg(const unsigned short* __restrict__ X,
                                             const int* __restrict__ off,
                                             const int* __restrict__ ssrc,
                                             const int* __restrict__ set_,
                                             const float* __restrict__ snorm,
                                             const float* __restrict__ comp,
                                             unsigned short* __restrict__ S) {
    int wid = threadIdx.x >> 6, lane = threadIdx.x & 63;
    int d = blockIdx.x * 4 + wid;
    if (d >= N_NODES) return;
    int p = off[d], pe = off[d + 1];
    float2 acc[4];
#pragma unroll
    for (int b = 0; b < 4; ++b) acc[b] = make_float2(0.0f, 0.0f);
    for (; p < pe; ++p) {
        int s = ssrc[p];
        int tt = set_[p];
        float w = snorm[p];
        unsigned int xp = *(const unsigned int*)(X + (size_t)s * 128 + 2 * lane);
        float x0 = b2f(xp & 0xffffu), x1 = b2f(xp >> 16);
        float4 cc = *(const float4*)(comp + tt * 4);
        float c0 = w * cc.x, c1 = w * cc.y, c2 = w * cc.z, c3 = w * cc.w;
        acc[0].x += c0 * x0; acc[0].y += c0 * x1;
        acc[1].x += c1 * x0; acc[1].y += c1 * x1;
        acc[2].x += c2 * x0; acc[2].y += c2 * x1;
        acc[3].x += c3 * x0; acc[3].y += c3 * x1;
    }
    size_t base = (size_t)d * 512 + 2 * lane;
#pragma unroll
    for (int b = 0; b < 4; ++b) {
        unsigned int pk = (unsigned int)f2b(acc[b].x) | ((unsigned int)f2b(acc[b].y) << 16);
        *(unsigned int*)(S + base + b * 128) = pk;
    }
}

// ---- GEMM: out[N,128] = relu?([S|X][N,640] @ WT^T + bias), bf16 out ------
__global__ __launch_bounds__(256) void k_gemm2(const unsigned short* __restrict__ S,
                                               const unsigned short* __restrict__ X,
                                               const unsigned short* __restrict__ WT,
                                               const float* __restrict__ bias,
                                               unsigned short* __restrict__ out,
                                               int do_relu) {
    __shared__ __align__(16) unsigned short As[128 * 128];
    __shared__ __align__(16) unsigned short Bs[128 * 128];

    const int t = threadIdx.x;
    const int rbase = blockIdx.x * 128;
    const int wid = t >> 6, lane = t & 63;
    const int quad = lane >> 4, lr = lane & 15;
    const int wr = wid >> 1, wc = wid & 1;

    floatx4 acc[4][4];
#pragma unroll
    for (int i = 0; i < 4; ++i)
#pragma unroll
        for (int j = 0; j < 4; ++j) acc[i][j] = (floatx4)0.0f;

    for (int kc = 0; kc < 5; ++kc) {
        const unsigned short* abase;
        size_t astride;
        if (kc < 4) { abase = S + kc * 128; astride = 512; }
        else        { abase = X;            astride = 128; }
#pragma unroll
        for (int i = 0; i < 8; ++i) {
            int idx = i * 256 + t;
            int row = idx >> 4, ch = idx & 15;
            int sch = (ch ^ (row & 15)) << 3;
            uint4 v = make_uint4(0u, 0u, 0u, 0u);
            int grow = rbase + row;
            if (grow < N_NODES) v = *(const uint4*)(abase + (size_t)grow * astride + ch * 8);
            *(uint4*)(As + row * 128 + sch) = v;
            uint4 w = *(const uint4*)(WT + (size_t)row * 640 + kc * 128 + ch * 8);
            *(uint4*)(Bs + row * 128 + sch) = w;
        }
        __syncthreads();
#pragma unroll
        for (int ks = 0; ks < 4; ++ks) {
            bf16x8 a[4], b[4];
#pragma unroll
            for (int i = 0; i < 4; ++i) {
                int ar = wr * 64 + i * 16 + lr;
                int br = wc * 64 + i * 16 + lr;
                int sch = ((ks * 4 + quad) ^ lr) << 3;
                a[i] = *(const bf16x8*)(As + ar * 128 + sch);
                b[i] = *(const bf16x8*)(Bs + br * 128 + sch);
            }
#pragma unroll
            for (int i = 0; i < 4; ++i)
#pragma unroll
                for (int j = 0; j < 4; ++j)
                    acc[i][j] = __builtin_amdgcn_mfma_f32_16x16x32_bf16(a[i], b[j], acc[i][j], 0, 0, 0);
        }
        __syncthreads();
    }

    // C/D layout: col=lane&15, row=quad*4+reg  [m89/m91-verified]
#pragma unroll
    for (int i = 0; i < 4; ++i) {
        int r0 = rbase + wr * 64 + i * 16 + quad * 4;
#pragma unroll
        for (int reg = 0; reg < 4; ++reg) {
            int grow = r0 + reg;
            if (grow >= N_NODES) continue;
#pragma unroll
            for (int j = 0; j < 4; ++j) {
                int col = wc * 64 + j * 16 + lr;
                float v = acc[i][j][reg] + bias[col];
                if (do_relu) v = v > 0.0f ? v : 0.0f;
                out[(size_t)grow * 128 + col] = f2b(v);
            }
        }
    }
}

// ---- DistMult score: one wave per edge, bf16 gathers, fp32 reduce --------
__global__ __launch_bounds__(256) void k_score(const unsigned short* __restrict__ xf,
                                               const int* __restrict__ src, const int* __restrict__ dst,
                                               const int* __restrict__ et,
                                               const unsigned short* __restrict__ relb,
                                               float* __restrict__ out, int E) {
    int wid = threadIdx.x >> 6, lane = threadIdx.x & 63;
    int e = blockIdx.x * 4 + wid;
    if (e >= E) return;
    int s = src[e], d = dst[e], tt = et[e];
    unsigned int ua = *(const unsigned int*)(xf + (size_t)s * 128 + 2 * lane);
    unsigned int ub = *(const unsigned int*)(xf + (size_t)d * 128 + 2 * lane);
    unsigned int ur = *(const unsigned int*)(relb + (size_t)tt * 128 + 2 * lane);
    float v = b2f(ua & 0xffffu) * b2f(ur & 0xffffu) * b2f(ub & 0xffffu)
            + b2f(ua >> 16) * b2f(ur >> 16) * b2f(ub >> 16);
#pragma unroll
    for (int o = 32; o > 0; o >>= 1) v += __shfl_down(v, o, 64);
    if (lane == 0) out[e] = v;
}

// ---- penalty = sum(rel^2), pure fp32 -------------------------------------
__global__ void k_penalty(const float* __restrict__ rel, float* __restrict__ out) {
    __shared__ float sm[256];
    float v = 0.0f;
    for (int i = threadIdx.x; i < RR * DIM; i += 256) { float x = rel[i]; v += x * x; }
    sm[threadIdx.x] = v;
    __syncthreads();
    for (int s = 128; s > 0; s >>= 1) {
        if (threadIdx.x < s) sm[threadIdx.x] += sm[threadIdx.x + s];
        __syncthreads();
    }
    if (threadIdx.x == 0) out[NE] = sm[0];
}

extern "C" void kernel_launch(void* const* d_in, const int* in_sizes, int n_in,
                              void* d_out, int out_size, void* d_ws, size_t ws_size,
                              hipStream_t stream) {
    (void)in_sizes; (void)n_in; (void)out_size; (void)ws_size;
    const int* edge_index = (const int*)d_in[0];
    const int* edge_type  = (const int*)d_in[1];
    const float* ent    = (const float*)d_in[2];
    const float* entb   = (const float*)d_in[3];
    const float* bases1 = (const float*)d_in[4];
    const float* comp1  = (const float*)d_in[5];
    const float* root1  = (const float*)d_in[6];
    const float* bias1  = (const float*)d_in[7];
    const float* bases2 = (const float*)d_in[8];
    const float* comp2  = (const float*)d_in[9];
    const float* root2  = (const float*)d_in[10];
    const float* bias2  = (const float*)d_in[11];
    const float* rel    = (const float*)d_in[12];
    const int* src = edge_index;
    const int* dst = edge_index + NE;

    char* ws = (char*)d_ws;
    size_t off_b = 0;
    auto alloc = [&](size_t bytes) { void* p = ws + off_b; off_b = (off_b + bytes + 255) & ~(size_t)255; return p; };

    unsigned short* sbuf = (unsigned short*)alloc((size_t)N_NODES * 512 * 2);  // 102.4 MB
    unsigned short* x1   = (unsigned short*)alloc((size_t)N_NODES * 128 * 2);  // 25.6 MB (also xf)
    unsigned short* x2   = (unsigned short*)alloc((size_t)N_NODES * 128 * 2);  // 25.6 MB
    unsigned short* wt1  = (unsigned short*)alloc(128 * 640 * 2);
    unsigned short* wt2  = (unsigned short*)alloc(128 * 640 * 2);
    unsigned short* relb = (unsigned short*)alloc(RR * DIM * 2);
    int*   deg    = (int*)alloc((size_t)N_NODES * 4);
    int*   cursor = (int*)alloc((size_t)N_NODES * 4);        // adjacent to deg
    int*   offv   = (int*)alloc((size_t)(N_NODES + 1) * 4);
    int*   bsum   = (int*)alloc(NBLK * 4);
    int*   boff   = (int*)alloc(NBLK * 4);
    int*   ssrc   = (int*)alloc((size_t)NE * 4);
    int*   set_   = (int*)alloc((size_t)NE * 4);
    float* snorm  = (float*)alloc((size_t)NE * 4);
    int*   counts = (int*)sbuf;                              // 40 MB alias; dead before sbuf written
    unsigned short* xf = x1;                                 // x1 dead after layer-1 GEMM

    float* out = (float*)d_out;

    hipMemsetAsync(counts, 0, (size_t)N_NODES * RR * 4, stream);
    hipMemsetAsync(deg, 0, (size_t)N_NODES * 2 * 4 + 256, stream);   // deg + cursor

    k_count<<<(NE + 255) / 256, 256, 0, stream>>>(dst, edge_type, counts, deg, NE);
    k_scan_block<<<NBLK, 256, 0, stream>>>(deg, bsum);
    k_scan_top<<<1, 256, 0, stream>>>(bsum, boff);
    k_scan_down<<<NBLK, 256, 0, stream>>>(deg, boff, offv);
    k_scatter<<<(NE + 255) / 256, 256, 0, stream>>>(src, dst, edge_type, counts, offv, cursor,
                                                    ssrc, set_, snorm, NE);
    k_x0<<<(N_NODES * 128 + 255) / 256, 256, 0, stream>>>(ent, entb, x1, N_NODES * 128);
    k_prep<<<(128 * 640 + 255) / 256, 256, 0, stream>>>(bases1, root1, bases2, root2, rel,
                                                        wt1, wt2, relb);

    // layer 1
    k_agg<<<(N_NODES + 3) / 4, 256, 0, stream>>>(x1, offv, ssrc, set_, snorm, comp1, sbuf);
    k_gemm2<<<(N_NODES + 127) / 128, 256, 0, stream>>>(sbuf, x1, wt1, bias1, x2, 1);
    // layer 2
    k_agg<<<(N_NODES + 3) / 4, 256, 0, stream>>>(x2, offv, ssrc, set_, snorm, comp2, sbuf);
    k_gemm2<<<(N_NODES + 127) / 128, 256, 0, stream>>>(sbuf, x2, wt2, bias2, xf, 0);
    // decode
    k_score<<<(NE + 3) / 4, 256, 0, stream>>>(xf, src, dst, edge_type, relb, out, NE);
    k_penalty<<<1, 256, 0, stream>>>(rel, out);
}